// Round 2
// baseline (173.134 us; speedup 1.0000x reference)
//
#include <hip/hip_runtime.h>
#include <cstddef>

#define B   4
#define D   512
#define T   2048
#define H   8
#define DH  64
#define NEG_SLOPE 0.2f
#define EPS 1e-6f
#define LOG2E 1.44269504088896340736f

typedef __attribute__((ext_vector_type(8))) short short8;   // 8 x bf16 (4 VGPRs)
typedef __attribute__((ext_vector_type(4))) float float4v;  // 4 x f32

__device__ __forceinline__ float bf2f(ushort u) {
    unsigned int x = ((unsigned int)u) << 16;
    return __builtin_bit_cast(float, x);
}
__device__ __forceinline__ ushort f2bf(float f) {
    unsigned int x = __builtin_bit_cast(unsigned int, f);
    x = x + 0x7fffu + ((x >> 16) & 1u);   // round-to-nearest-even
    return (ushort)(x >> 16);
}

// -----------------------------------------------------------------------------
// Kernel A: 64x64-tiled transpose fp32 -> bf16, optional leaky-ReLU.
// Block (0,0,0) also zeroes zbuf (ssq accumulator) when zbuf != nullptr.
// -----------------------------------------------------------------------------
__global__ __launch_bounds__(256) void transpose_lrelu(const float* __restrict__ src,
                                                       ushort* __restrict__ dst,
                                                       int src_ld, int dst_ld,
                                                       size_t src_mstride, size_t dst_mstride,
                                                       int do_lrelu,
                                                       float* __restrict__ zbuf, int zcount) {
    const int tid = threadIdx.x;
    if (zbuf != nullptr && blockIdx.x == 0 && blockIdx.y == 0 && blockIdx.z == 0) {
        for (int i = tid; i < zcount; i += 256) zbuf[i] = 0.f;
    }

    const int c0 = blockIdx.x * 64, r0 = blockIdx.y * 64;
    const float* s = src + blockIdx.z * src_mstride + (size_t)r0 * src_ld + c0;
    ushort*      d = dst + blockIdx.z * dst_mstride + (size_t)c0 * dst_ld + r0;

    __shared__ float Ls[64][68];

    const int rl = tid >> 4, c4 = (tid & 15) * 4;
    #pragma unroll
    for (int p = 0; p < 4; ++p) {
        float4 v = *(const float4*)(s + (size_t)(rl + p * 16) * src_ld + c4);
        if (do_lrelu) {
            v.x = fmaxf(v.x, NEG_SLOPE * v.x);
            v.y = fmaxf(v.y, NEG_SLOPE * v.y);
            v.z = fmaxf(v.z, NEG_SLOPE * v.z);
            v.w = fmaxf(v.w, NEG_SLOPE * v.w);
        }
        *(float4*)&Ls[rl + p * 16][c4] = v;
    }
    __syncthreads();

    const int tl = tid >> 2;
    #pragma unroll
    for (int it = 0; it < 2; ++it) {
        int ch = (tid & 3) + it * 4;
        ushort o[8];
        #pragma unroll
        for (int j = 0; j < 8; ++j) o[j] = f2bf(Ls[ch * 8 + j][tl]);
        *(uint4*)(d + (size_t)tl * dst_ld + ch * 8) = *(uint4*)o;
    }
}

// -----------------------------------------------------------------------------
// Kernel B: QKV GEMM via bf16 MFMA. C[b][t][gd] = sum_d xT[b][t][d] * WT[gd][d]
// Q/K heads -> hb[t][dh]; V heads -> vT[dd][t]. Accumulates per-channel sumsq.
// -----------------------------------------------------------------------------
__global__ __launch_bounds__(256) void qkv_mm(const ushort* __restrict__ xT,
                                              const ushort* __restrict__ WT,
                                              ushort* __restrict__ hb,
                                              ushort* __restrict__ vT,
                                              float* __restrict__ ssq) {
    const int tid = threadIdx.x, wave = tid >> 6, lane = tid & 63;
    const int quad = lane >> 4, l16 = lane & 15;
    const int wr = wave >> 1, wc = wave & 1;
    const int t0  = blockIdx.x * 128;
    const int gd0 = blockIdx.y * 128;
    const int b   = blockIdx.z;

    __shared__ ushort At[128 * 64];
    __shared__ ushort Bt[128 * 64];

    const ushort* xb = xT + (size_t)b * T * D + (size_t)t0 * D;
    const ushort* wb = WT + (size_t)gd0 * D;

    const int srow = lane >> 3;
    const int csrc = (lane & 7) ^ srow;

    float4v acc[4][4];
    #pragma unroll
    for (int i = 0; i < 4; ++i)
        #pragma unroll
        for (int j = 0; j < 4; ++j) acc[i][j] = (float4v){0.f, 0.f, 0.f, 0.f};

    for (int k0 = 0; k0 < D; k0 += 64) {
        #pragma unroll
        for (int i = 0; i < 4; ++i) {
            int rbase = wave * 32 + i * 8;
            int row = rbase + srow;
            const ushort* ga = xb + (size_t)row * D + k0 + csrc * 8;
            const ushort* gb = wb + (size_t)row * D + k0 + csrc * 8;
            __builtin_amdgcn_global_load_lds(
                (const __attribute__((address_space(1))) unsigned int*)ga,
                (__attribute__((address_space(3))) unsigned int*)&At[rbase * 64], 16, 0, 0);
            __builtin_amdgcn_global_load_lds(
                (const __attribute__((address_space(1))) unsigned int*)gb,
                (__attribute__((address_space(3))) unsigned int*)&Bt[rbase * 64], 16, 0, 0);
        }
        __syncthreads();

        #pragma unroll
        for (int kh = 0; kh < 2; ++kh) {
            short8 aF[4], bF[4];
            #pragma unroll
            for (int mt = 0; mt < 4; ++mt) {
                int row = wr * 64 + mt * 16 + l16;
                aF[mt] = *(const short8*)&At[row * 64 + (((kh * 4 + quad) ^ (l16 & 7)) * 8)];
            }
            #pragma unroll
            for (int nt = 0; nt < 4; ++nt) {
                int row = wc * 64 + nt * 16 + l16;
                bF[nt] = *(const short8*)&Bt[row * 64 + (((kh * 4 + quad) ^ (l16 & 7)) * 8)];
            }
            #pragma unroll
            for (int mt = 0; mt < 4; ++mt)
                #pragma unroll
                for (int nt = 0; nt < 4; ++nt)
                    acc[mt][nt] = __builtin_amdgcn_mfma_f32_16x16x32_bf16(
                        aF[mt], bF[nt], acc[mt][nt], 0, 0, 0);
        }
        __syncthreads();
    }

    const int g = blockIdx.y * 2 + wc;       // 0..23
    const int n = g >> 3, hh = g & 7;
    float colsq[4] = {0.f, 0.f, 0.f, 0.f};

    if (n < 2) {
        ushort* hbase = hb + (((size_t)n * B + b) * H + hh) * (size_t)T * DH;
        #pragma unroll
        for (int mt = 0; mt < 4; ++mt) {
            #pragma unroll
            for (int nt = 0; nt < 4; ++nt) {
                float4v c = acc[mt][nt];
                int dd = nt * 16 + l16;
                #pragma unroll
                for (int r = 0; r < 4; ++r) {
                    int t = t0 + wr * 64 + mt * 16 + quad * 4 + r;
                    hbase[(size_t)t * DH + dd] = f2bf(c[r]);
                    colsq[nt] += c[r] * c[r];
                }
            }
        }
    } else {
        ushort* vbase = vT + ((size_t)b * H + hh) * (size_t)DH * T;
        #pragma unroll
        for (int mt = 0; mt < 4; ++mt) {
            #pragma unroll
            for (int nt = 0; nt < 4; ++nt) {
                float4v c = acc[mt][nt];
                int dd = nt * 16 + l16;
                int t  = t0 + wr * 64 + mt * 16 + quad * 4;
                ushort4 pk;
                pk.x = f2bf(c[0]); pk.y = f2bf(c[1]);
                pk.z = f2bf(c[2]); pk.w = f2bf(c[3]);
                *(ushort4*)(vbase + (size_t)dd * T + t) = pk;
                colsq[nt] += c[0]*c[0] + c[1]*c[1] + c[2]*c[2] + c[3]*c[3];
            }
        }
    }
    #pragma unroll
    for (int nt = 0; nt < 4; ++nt) {
        float s = colsq[nt];
        s += __shfl_xor(s, 16);
        s += __shfl_xor(s, 32);
        if (quad == 0)
            atomicAdd(&ssq[(((size_t)n * B + b) * H + hh) * 64 + nt * 16 + l16], s);
    }
}

// -----------------------------------------------------------------------------
// Kernel C: flash attention, S^T = K*Q^T, NO online max (scores ~N(0,1):
// exp2 cannot overflow fp32/bf16 exponent range). log2e folded into Q scale.
//
// Round-2 bisect: KEEP (a) 32 queries/wave (2 groups of 16; aK ds_reads shared
// by both groups -> K-read LDS traffic per MFMA halved) and (b) V fragments
// loaded DIRECTLY from global (vT layout makes each fragment a contiguous
// 16B/lane load; per-XCD V working set 2MB = L2-resident via head-major block
// remap). REVERT (c) single-barrier K double-buffer -> proven round-0
// stage;barrier;compute;barrier single-buffer structure, and (d) cvt_pk asm
// -> proven +0x8000 + v_perm bf16 pack. LDS ops/tile/wave: 12 b128 reads +
// 8 b64 writes per 32 MFMAs (was 18 reads + 4 writes per 16 MFMAs).
// -----------------------------------------------------------------------------
__global__ __launch_bounds__(256, 2) void flash_attn(const ushort* __restrict__ hb,
                                                     const ushort* __restrict__ vT,
                                                     const float* __restrict__ ssq,
                                                     const float* __restrict__ norm_w,
                                                     float* __restrict__ out) {
    const int tid  = threadIdx.x;
    const int wave = tid >> 6;
    const int lane = tid & 63;
    const int quad = lane >> 4;
    const int l16  = lane & 15;

    // XCD-locality remap: all 16 t-tiles of a head land on one XCD
    const int lin  = blockIdx.x;                            // 0..511
    const int head = ((lin & 7) << 2) | ((lin >> 3) & 3);   // b*H+hh
    const int t0   = (lin >> 5) * 128;
    const int b    = head >> 3, hh = head & 7;

    const size_t slab = (size_t)B * H * T * DH;
    const ushort* qp = hb + (size_t)head * T * DH;
    const ushort* kp = hb + slab + (size_t)head * T * DH;
    const ushort* vp = vT + (size_t)head * DH * T;

    __shared__ ushort Kt[64 * 64];        // 8 KB, K tile (single-buffered)
    __shared__ ushort Pb[4][2][16 * 64];  // 16 KB, wave-private, per q-group
    __shared__ float fqk[64], sv[64];

    if (tid < 64) {
        float nw = norm_w[0];
        float mq = ssq[(0 * B * H + head) * 64 + tid] * (1.0f / T) + EPS;
        float mk = ssq[(1 * B * H + head) * 64 + tid] * (1.0f / T) + EPS;
        float mv = ssq[(2 * B * H + head) * 64 + tid] * (1.0f / T) + EPS;
        fqk[tid] = nw * nw * rsqrtf(mq) * rsqrtf(mk) * 0.125f * LOG2E;
        sv[tid]  = nw * rsqrtf(mv);
    }
    __syncthreads();

    // ---- Q B-frags: 2 query groups of 16 per wave, pre-scaled by fqk
    short8 bQ[2][2];
    #pragma unroll
    for (int g = 0; g < 2; ++g) {
        const ushort* qr = qp + (size_t)(t0 + wave * 32 + g * 16 + l16) * DH;
        #pragma unroll
        for (int kh = 0; kh < 2; ++kh) {
            short8 raw = *(const short8*)(qr + kh * 32 + quad * 8);
            #pragma unroll
            for (int j = 0; j < 8; ++j) {
                float f = bf2f((ushort)raw[j]) * fqk[kh * 32 + quad * 8 + j];
                bQ[g][kh][j] = (short)f2bf(f);
            }
        }
    }

    // ---- K staging lane constants (pre-swizzled global source, linear LDS)
    const int srow = lane >> 3;
    const int csrc = (lane & 7) ^ srow;
    const ushort* kA = kp + (size_t)(wave * 16 + srow) * DH + csrc * 8;
    const ushort* kB = kp + (size_t)(wave * 16 + 8 + srow) * DH + csrc * 8;

    float l_run[2] = {0.f, 0.f};
    float4v O[2][4];
    #pragma unroll
    for (int g = 0; g < 2; ++g)
        #pragma unroll
        for (int dt = 0; dt < 4; ++dt) O[g][dt] = (float4v){0.f, 0.f, 0.f, 0.f};

    for (int j0 = 0; j0 < T; j0 += 64) {
        // ---- stage K tile (async global->LDS)
        __builtin_amdgcn_global_load_lds(
            (const __attribute__((address_space(1))) unsigned int*)(kA + (size_t)j0 * DH),
            (__attribute__((address_space(3))) unsigned int*)&Kt[(wave * 16) * 64], 16, 0, 0);
        __builtin_amdgcn_global_load_lds(
            (const __attribute__((address_space(1))) unsigned int*)(kB + (size_t)j0 * DH),
            (__attribute__((address_space(3))) unsigned int*)&Kt[(wave * 16 + 8) * 64], 16, 0, 0);

        // ---- V fragments for THIS tile: direct 16B/lane global loads
        // (in flight across the barrier's vmcnt drain; consumed in PV)
        short8 aV[2][4];
        #pragma unroll
        for (int kh = 0; kh < 2; ++kh)
            #pragma unroll
            for (int dt = 0; dt < 4; ++dt)
                aV[kh][dt] = *(const short8*)(vp + (size_t)(dt * 16 + l16) * T
                                              + j0 + kh * 32 + quad * 8);

        __syncthreads();

        // ---- S^T = K * Q^T for both query groups (aK reads shared)
        float4v S[2][4];
        #pragma unroll
        for (int g = 0; g < 2; ++g)
            #pragma unroll
            for (int mt = 0; mt < 4; ++mt) S[g][mt] = (float4v){0.f, 0.f, 0.f, 0.f};
        #pragma unroll
        for (int kh = 0; kh < 2; ++kh) {
            short8 aK[4];
            #pragma unroll
            for (int mt = 0; mt < 4; ++mt) {
                int row = mt * 16 + l16;
                aK[mt] = *(const short8*)&Kt[row * 64 + (((kh * 4 + quad) ^ (l16 & 7)) * 8)];
            }
            #pragma unroll
            for (int g = 0; g < 2; ++g)
                #pragma unroll
                for (int mt = 0; mt < 4; ++mt)
                    S[g][mt] = __builtin_amdgcn_mfma_f32_16x16x32_bf16(
                        aK[mt], bQ[g][kh], S[g][mt], 0, 0, 0);
        }

        // ---- P = exp2(S), partial l, pack to bf16 via v_perm (proven path)
        #pragma unroll
        for (int g = 0; g < 2; ++g) {
            #pragma unroll
            for (int mt = 0; mt < 4; ++mt) {
                float p0 = __builtin_amdgcn_exp2f(S[g][mt][0]);
                float p1 = __builtin_amdgcn_exp2f(S[g][mt][1]);
                float p2 = __builtin_amdgcn_exp2f(S[g][mt][2]);
                float p3 = __builtin_amdgcn_exp2f(S[g][mt][3]);
                l_run[g] += (p0 + p1) + (p2 + p3);
                unsigned int a0 = __builtin_bit_cast(unsigned int, p0) + 0x8000u;
                unsigned int a1 = __builtin_bit_cast(unsigned int, p1) + 0x8000u;
                unsigned int a2 = __builtin_bit_cast(unsigned int, p2) + 0x8000u;
                unsigned int a3 = __builtin_bit_cast(unsigned int, p3) + 0x8000u;
                uint2 pk;
                pk.x = __builtin_amdgcn_perm(a1, a0, 0x07060302u);
                pk.y = __builtin_amdgcn_perm(a3, a2, 0x07060302u);
                *(uint2*)&Pb[wave][g][l16 * 64 + (((mt * 2 + (quad >> 1)) ^ (l16 & 7)) * 8)
                                      + (quad & 1) * 4] = pk;
            }
        }

        // ---- O^T += V^T * P^T (Pb wave-private: no barrier; aV from regs)
        #pragma unroll
        for (int g = 0; g < 2; ++g) {
            #pragma unroll
            for (int kh = 0; kh < 2; ++kh) {
                short8 bP = *(const short8*)&Pb[wave][g][l16 * 64 + (((kh * 4 + quad) ^ (l16 & 7)) * 8)];
                #pragma unroll
                for (int dt = 0; dt < 4; ++dt)
                    O[g][dt] = __builtin_amdgcn_mfma_f32_16x16x32_bf16(
                        aV[kh][dt], bP, O[g][dt], 0, 0, 0);
            }
        }

        __syncthreads();     // all waves done reading Kt before next stage
    }

    // ---- epilogue: cross-quad l reduction per group, then store
    #pragma unroll
    for (int g = 0; g < 2; ++g) {
        float rs = l_run[g];
        rs += __shfl_xor(rs, 16);
        rs += __shfl_xor(rs, 32);
        float inv = 1.f / rs;
        const int t = t0 + wave * 32 + g * 16 + l16;
        #pragma unroll
        for (int dt = 0; dt < 4; ++dt) {
            #pragma unroll
            for (int r = 0; r < 4; ++r) {
                int dd = dt * 16 + quad * 4 + r;
                out[((size_t)b * D + hh * DH + dd) * T + t] = O[g][dt][r] * inv * sv[dd];
            }
        }
    }
}

// -----------------------------------------------------------------------------
extern "C" void kernel_launch(void* const* d_in, const int* in_sizes, int n_in,
                              void* d_out, int out_size, void* d_ws, size_t ws_size,
                              hipStream_t stream) {
    const float* x      = (const float*)d_in[0];
    const float* qkv    = (const float*)d_in[1];
    const float* norm_w = (const float*)d_in[2];
    float* out = (float*)d_out;

    const size_t HB_BYTES = (size_t)2 * B * H * T * DH * 2;   // Q+K slabs
    const size_t VT_BYTES = (size_t)B * H * DH * T * 2;
    const size_t XT_BYTES = (size_t)B * T * D * 2;
    const size_t WT_BYTES = (size_t)3 * H * DH * D * 2;
    ushort* hb  = (ushort*)d_ws;
    ushort* vT  = (ushort*)((char*)d_ws + HB_BYTES);
    ushort* xT  = (ushort*)((char*)d_ws + HB_BYTES + VT_BYTES);
    ushort* WT  = (ushort*)((char*)d_ws + HB_BYTES + VT_BYTES + XT_BYTES);
    float*  ssq = (float*)((char*)d_ws + HB_BYTES + VT_BYTES + XT_BYTES + WT_BYTES);
    const int SSQ_N = 3 * B * H * DH;

    // x transpose also zeroes ssq (block 0) — it strictly precedes qkv_mm.
    transpose_lrelu<<<dim3(T / 64, D / 64, B), 256, 0, stream>>>(
        x, xT, T, D, (size_t)D * T, (size_t)T * D, 1, ssq, SSQ_N);
    transpose_lrelu<<<dim3(DH / 64, D / 64, 3 * H), 256, 0, stream>>>(
        qkv, WT, DH, D, (size_t)D * DH, (size_t)DH * D, 0, nullptr, 0);

    qkv_mm<<<dim3(T / 128, (3 * H * DH) / 128, B), 256, 0, stream>>>(xT, WT, hb, vT, ssq);
    flash_attn<<<dim3((T / 128) * B * H), 256, 0, stream>>>(hb, vT, ssq, norm_w, out);
}

// Round 3
// 154.239 us; speedup vs baseline: 1.1225x; 1.1225x over previous
//
#include <hip/hip_runtime.h>
#include <cstddef>

#define B   4
#define D   512
#define T   2048
#define H   8
#define DH  64
#define NEG_SLOPE 0.2f
#define EPS 1e-6f
#define LOG2E 1.44269504088896340736f

typedef __attribute__((ext_vector_type(8))) short short8;   // 8 x bf16 (4 VGPRs)
typedef __attribute__((ext_vector_type(4))) float float4v;  // 4 x f32

__device__ __forceinline__ float bf2f(ushort u) {
    unsigned int x = ((unsigned int)u) << 16;
    return __builtin_bit_cast(float, x);
}
__device__ __forceinline__ ushort f2bf(float f) {
    unsigned int x = __builtin_bit_cast(unsigned int, f);
    x = x + 0x7fffu + ((x >> 16) & 1u);   // round-to-nearest-even
    return (ushort)(x >> 16);
}

// -----------------------------------------------------------------------------
// Kernel A: 64x64-tiled transpose fp32 -> bf16, optional leaky-ReLU.
// Block (0,0,0) also zeroes zbuf (ssq accumulator) when zbuf != nullptr.
// -----------------------------------------------------------------------------
__global__ __launch_bounds__(256) void transpose_lrelu(const float* __restrict__ src,
                                                       ushort* __restrict__ dst,
                                                       int src_ld, int dst_ld,
                                                       size_t src_mstride, size_t dst_mstride,
                                                       int do_lrelu,
                                                       float* __restrict__ zbuf, int zcount) {
    const int tid = threadIdx.x;
    if (zbuf != nullptr && blockIdx.x == 0 && blockIdx.y == 0 && blockIdx.z == 0) {
        for (int i = tid; i < zcount; i += 256) zbuf[i] = 0.f;
    }

    const int c0 = blockIdx.x * 64, r0 = blockIdx.y * 64;
    const float* s = src + blockIdx.z * src_mstride + (size_t)r0 * src_ld + c0;
    ushort*      d = dst + blockIdx.z * dst_mstride + (size_t)c0 * dst_ld + r0;

    __shared__ float Ls[64][68];

    const int rl = tid >> 4, c4 = (tid & 15) * 4;
    #pragma unroll
    for (int p = 0; p < 4; ++p) {
        float4 v = *(const float4*)(s + (size_t)(rl + p * 16) * src_ld + c4);
        if (do_lrelu) {
            v.x = fmaxf(v.x, NEG_SLOPE * v.x);
            v.y = fmaxf(v.y, NEG_SLOPE * v.y);
            v.z = fmaxf(v.z, NEG_SLOPE * v.z);
            v.w = fmaxf(v.w, NEG_SLOPE * v.w);
        }
        *(float4*)&Ls[rl + p * 16][c4] = v;
    }
    __syncthreads();

    const int tl = tid >> 2;
    #pragma unroll
    for (int it = 0; it < 2; ++it) {
        int ch = (tid & 3) + it * 4;
        ushort o[8];
        #pragma unroll
        for (int j = 0; j < 8; ++j) o[j] = f2bf(Ls[ch * 8 + j][tl]);
        *(uint4*)(d + (size_t)tl * dst_ld + ch * 8) = *(uint4*)o;
    }
}

// -----------------------------------------------------------------------------
// Kernel B: QKV GEMM via bf16 MFMA. C[b][t][gd] = sum_d xT[b][t][d] * WT[gd][d]
// Q/K heads -> hb[t][dh]; V heads -> vT[dd][t]. Accumulates per-channel sumsq.
// -----------------------------------------------------------------------------
__global__ __launch_bounds__(256) void qkv_mm(const ushort* __restrict__ xT,
                                              const ushort* __restrict__ WT,
                                              ushort* __restrict__ hb,
                                              ushort* __restrict__ vT,
                                              float* __restrict__ ssq) {
    const int tid = threadIdx.x, wave = tid >> 6, lane = tid & 63;
    const int quad = lane >> 4, l16 = lane & 15;
    const int wr = wave >> 1, wc = wave & 1;
    const int t0  = blockIdx.x * 128;
    const int gd0 = blockIdx.y * 128;
    const int b   = blockIdx.z;

    __shared__ ushort At[128 * 64];
    __shared__ ushort Bt[128 * 64];

    const ushort* xb = xT + (size_t)b * T * D + (size_t)t0 * D;
    const ushort* wb = WT + (size_t)gd0 * D;

    const int srow = lane >> 3;
    const int csrc = (lane & 7) ^ srow;

    float4v acc[4][4];
    #pragma unroll
    for (int i = 0; i < 4; ++i)
        #pragma unroll
        for (int j = 0; j < 4; ++j) acc[i][j] = (float4v){0.f, 0.f, 0.f, 0.f};

    for (int k0 = 0; k0 < D; k0 += 64) {
        #pragma unroll
        for (int i = 0; i < 4; ++i) {
            int rbase = wave * 32 + i * 8;
            int row = rbase + srow;
            const ushort* ga = xb + (size_t)row * D + k0 + csrc * 8;
            const ushort* gb = wb + (size_t)row * D + k0 + csrc * 8;
            __builtin_amdgcn_global_load_lds(
                (const __attribute__((address_space(1))) unsigned int*)ga,
                (__attribute__((address_space(3))) unsigned int*)&At[rbase * 64], 16, 0, 0);
            __builtin_amdgcn_global_load_lds(
                (const __attribute__((address_space(1))) unsigned int*)gb,
                (__attribute__((address_space(3))) unsigned int*)&Bt[rbase * 64], 16, 0, 0);
        }
        __syncthreads();

        #pragma unroll
        for (int kh = 0; kh < 2; ++kh) {
            short8 aF[4], bF[4];
            #pragma unroll
            for (int mt = 0; mt < 4; ++mt) {
                int row = wr * 64 + mt * 16 + l16;
                aF[mt] = *(const short8*)&At[row * 64 + (((kh * 4 + quad) ^ (l16 & 7)) * 8)];
            }
            #pragma unroll
            for (int nt = 0; nt < 4; ++nt) {
                int row = wc * 64 + nt * 16 + l16;
                bF[nt] = *(const short8*)&Bt[row * 64 + (((kh * 4 + quad) ^ (l16 & 7)) * 8)];
            }
            #pragma unroll
            for (int mt = 0; mt < 4; ++mt)
                #pragma unroll
                for (int nt = 0; nt < 4; ++nt)
                    acc[mt][nt] = __builtin_amdgcn_mfma_f32_16x16x32_bf16(
                        aF[mt], bF[nt], acc[mt][nt], 0, 0, 0);
        }
        __syncthreads();
    }

    const int g = blockIdx.y * 2 + wc;       // 0..23
    const int n = g >> 3, hh = g & 7;
    float colsq[4] = {0.f, 0.f, 0.f, 0.f};

    if (n < 2) {
        ushort* hbase = hb + (((size_t)n * B + b) * H + hh) * (size_t)T * DH;
        #pragma unroll
        for (int mt = 0; mt < 4; ++mt) {
            #pragma unroll
            for (int nt = 0; nt < 4; ++nt) {
                float4v c = acc[mt][nt];
                int dd = nt * 16 + l16;
                #pragma unroll
                for (int r = 0; r < 4; ++r) {
                    int t = t0 + wr * 64 + mt * 16 + quad * 4 + r;
                    hbase[(size_t)t * DH + dd] = f2bf(c[r]);
                    colsq[nt] += c[r] * c[r];
                }
            }
        }
    } else {
        ushort* vbase = vT + ((size_t)b * H + hh) * (size_t)DH * T;
        #pragma unroll
        for (int mt = 0; mt < 4; ++mt) {
            #pragma unroll
            for (int nt = 0; nt < 4; ++nt) {
                float4v c = acc[mt][nt];
                int dd = nt * 16 + l16;
                int t  = t0 + wr * 64 + mt * 16 + quad * 4;
                ushort4 pk;
                pk.x = f2bf(c[0]); pk.y = f2bf(c[1]);
                pk.z = f2bf(c[2]); pk.w = f2bf(c[3]);
                *(ushort4*)(vbase + (size_t)dd * T + t) = pk;
                colsq[nt] += c[0]*c[0] + c[1]*c[1] + c[2]*c[2] + c[3]*c[3];
            }
        }
    }
    #pragma unroll
    for (int nt = 0; nt < 4; ++nt) {
        float s = colsq[nt];
        s += __shfl_xor(s, 16);
        s += __shfl_xor(s, 32);
        if (quad == 0)
            atomicAdd(&ssq[(((size_t)n * B + b) * H + hh) * 64 + nt * 16 + l16], s);
    }
}

// -----------------------------------------------------------------------------
// Kernel C: flash attention, S^T = K*Q^T, NO online max (scores ~N(0,1):
// exp2 cannot overflow fp32/bf16 exponent range). log2e folded into Q scale.
//
// Round-3: back to the round-0 structure (16 q/wave, grid 1024 = 16 waves/CU,
// V staged in LDS, v_perm pack) — round 2 proved the kernel is LATENCY-bound,
// not LDS-throughput-bound (halving waves + direct-V regressed 61->75us).
// Single change vs round 0: hide the stage latency. K is double-buffered and
// K(j+1) is issued at the TOP of iter j; V(j) is also issued at the top (its
// consumer PV sits after the mid-tile barrier). Both drains now happen a full
// QK+softmax phase (~500cy) after issue instead of immediately. Barrier count
// unchanged (2/tile). LDS 32.5KB -> still 4 blocks/CU.
// -----------------------------------------------------------------------------
__global__ __launch_bounds__(256, 4) void flash_attn(const ushort* __restrict__ hb,
                                                     const ushort* __restrict__ vT,
                                                     const float* __restrict__ ssq,
                                                     const float* __restrict__ norm_w,
                                                     float* __restrict__ out) {
    const int tid  = threadIdx.x;
    const int wave = tid >> 6;
    const int lane = tid & 63;
    const int quad = lane >> 4;
    const int l16  = lane & 15;

    // XCD-locality remap: all 32 t-tiles of a head land on one XCD
    const int lin  = blockIdx.x;
    const int head = ((lin & 7) << 2) | ((lin >> 3) & 3);   // b*H+hh
    const int t0   = (lin >> 5) * 64;
    const int b    = head >> 3, hh = head & 7;

    const size_t slab = (size_t)B * H * T * DH;
    const ushort* qp = hb + (size_t)head * T * DH;
    const ushort* kp = hb + slab + (size_t)head * T * DH;
    const ushort* vp = vT + (size_t)head * DH * T;

    __shared__ ushort Kt[2][64 * 64];     // 16 KB, double-buffered K tile
    __shared__ ushort Vt[64 * 64];        // 8 KB, single-buffered V tile
    __shared__ ushort Pb[4][16 * 64];     // 8 KB, wave-private quadrants
    __shared__ float fqk[64], sv[64];

    if (tid < 64) {
        float nw = norm_w[0];
        float mq = ssq[(0 * B * H + head) * 64 + tid] * (1.0f / T) + EPS;
        float mk = ssq[(1 * B * H + head) * 64 + tid] * (1.0f / T) + EPS;
        float mv = ssq[(2 * B * H + head) * 64 + tid] * (1.0f / T) + EPS;
        fqk[tid] = nw * nw * rsqrtf(mq) * rsqrtf(mk) * 0.125f * LOG2E;
        sv[tid]  = nw * rsqrtf(mv);
    }

    // ---- staging lane constants (pre-swizzled global source, linear LDS)
    const int srow = lane >> 3;
    const int csrc = (lane & 7) ^ srow;
    const ushort* kA = kp + (size_t)(wave * 16 + srow) * DH + csrc * 8;
    const ushort* kB = kp + (size_t)(wave * 16 + 8 + srow) * DH + csrc * 8;
    const ushort* vA = vp + (size_t)(wave * 16 + srow) * T + csrc * 8;
    const ushort* vB = vp + (size_t)(wave * 16 + 8 + srow) * T + csrc * 8;

    // ---- prologue: stage K tile 0 into buffer 0 (drained by the barrier below)
    __builtin_amdgcn_global_load_lds(
        (const __attribute__((address_space(1))) unsigned int*)kA,
        (__attribute__((address_space(3))) unsigned int*)&Kt[0][(wave * 16) * 64], 16, 0, 0);
    __builtin_amdgcn_global_load_lds(
        (const __attribute__((address_space(1))) unsigned int*)kB,
        (__attribute__((address_space(3))) unsigned int*)&Kt[0][(wave * 16 + 8) * 64], 16, 0, 0);

    // ---- Q B-frags (col = query = l16), pre-scaled by fqk (incl. log2e)
    __syncthreads();          // fqk/sv ready + K(0) staged & visible
    short8 bQ[2];
    {
        const ushort* qr = qp + (size_t)(t0 + wave * 16 + l16) * DH;
        #pragma unroll
        for (int kh = 0; kh < 2; ++kh) {
            short8 raw = *(const short8*)(qr + kh * 32 + quad * 8);
            #pragma unroll
            for (int j = 0; j < 8; ++j) {
                float f = bf2f((ushort)raw[j]) * fqk[kh * 32 + quad * 8 + j];
                bQ[kh][j] = (short)f2bf(f);
            }
        }
    }

    float l_run = 0.f;
    float4v O[4];
    #pragma unroll
    for (int dt = 0; dt < 4; ++dt) O[dt] = (float4v){0.f, 0.f, 0.f, 0.f};

    int cur = 0;
    for (int j0 = 0; j0 < T; j0 += 64) {
        // ---- issue V(j) stage now; consumed after the mid-tile barrier.
        // (All waves finished reading Vt[j-1] before the end barrier of j-1.)
        __builtin_amdgcn_global_load_lds(
            (const __attribute__((address_space(1))) unsigned int*)(vA + j0),
            (__attribute__((address_space(3))) unsigned int*)&Vt[(wave * 16) * 64], 16, 0, 0);
        __builtin_amdgcn_global_load_lds(
            (const __attribute__((address_space(1))) unsigned int*)(vB + j0),
            (__attribute__((address_space(3))) unsigned int*)&Vt[(wave * 16 + 8) * 64], 16, 0, 0);

        // ---- issue K(j+1) prefetch into the other buffer
        if (j0 + 64 < T) {
            __builtin_amdgcn_global_load_lds(
                (const __attribute__((address_space(1))) unsigned int*)(kA + (size_t)(j0 + 64) * DH),
                (__attribute__((address_space(3))) unsigned int*)&Kt[cur ^ 1][(wave * 16) * 64], 16, 0, 0);
            __builtin_amdgcn_global_load_lds(
                (const __attribute__((address_space(1))) unsigned int*)(kB + (size_t)(j0 + 64) * DH),
                (__attribute__((address_space(3))) unsigned int*)&Kt[cur ^ 1][(wave * 16 + 8) * 64], 16, 0, 0);
        }

        // ---- S^T = K * Q^T from Kt[cur] (staged last iter, already visible)
        float4v S[4];
        #pragma unroll
        for (int mt = 0; mt < 4; ++mt) S[mt] = (float4v){0.f, 0.f, 0.f, 0.f};
        #pragma unroll
        for (int kh = 0; kh < 2; ++kh) {
            #pragma unroll
            for (int mt = 0; mt < 4; ++mt) {
                int row = mt * 16 + l16;
                short8 aK = *(const short8*)&Kt[cur][row * 64 + (((kh * 4 + quad) ^ (l16 & 7)) * 8)];
                S[mt] = __builtin_amdgcn_mfma_f32_16x16x32_bf16(aK, bQ[kh], S[mt], 0, 0, 0);
            }
        }

        // ---- P = exp2(S), accumulate partial l, pack to bf16 via v_perm
        #pragma unroll
        for (int mt = 0; mt < 4; ++mt) {
            float p0 = __builtin_amdgcn_exp2f(S[mt][0]);
            float p1 = __builtin_amdgcn_exp2f(S[mt][1]);
            float p2 = __builtin_amdgcn_exp2f(S[mt][2]);
            float p3 = __builtin_amdgcn_exp2f(S[mt][3]);
            l_run += (p0 + p1) + (p2 + p3);
            unsigned int a0 = __builtin_bit_cast(unsigned int, p0) + 0x8000u;
            unsigned int a1 = __builtin_bit_cast(unsigned int, p1) + 0x8000u;
            unsigned int a2 = __builtin_bit_cast(unsigned int, p2) + 0x8000u;
            unsigned int a3 = __builtin_bit_cast(unsigned int, p3) + 0x8000u;
            uint2 pk;
            pk.x = __builtin_amdgcn_perm(a1, a0, 0x07060302u);
            pk.y = __builtin_amdgcn_perm(a3, a2, 0x07060302u);
            *(uint2*)&Pb[wave][l16 * 64 + (((mt * 2 + (quad >> 1)) ^ (l16 & 7)) * 8)
                               + (quad & 1) * 4] = pk;
        }

        __syncthreads();      // V(j) + K(j+1) landed (issued ~a full phase ago)

        // ---- O^T += V^T * P^T (Pb wave-private)
        #pragma unroll
        for (int kh = 0; kh < 2; ++kh) {
            short8 bP = *(const short8*)&Pb[wave][l16 * 64 + (((kh * 4 + quad) ^ (l16 & 7)) * 8)];
            #pragma unroll
            for (int dt = 0; dt < 4; ++dt) {
                int row = dt * 16 + l16;
                short8 aV = *(const short8*)&Vt[row * 64 + (((kh * 4 + quad) ^ (row & 7)) * 8)];
                O[dt] = __builtin_amdgcn_mfma_f32_16x16x32_bf16(aV, bP, O[dt], 0, 0, 0);
            }
        }

        __syncthreads();      // all waves done reading Vt before next V stage
        cur ^= 1;
    }

    // ---- epilogue: cross-quad l reduction (once), then store
    float rs = l_run;
    rs += __shfl_xor(rs, 16);
    rs += __shfl_xor(rs, 32);
    float inv = 1.f / rs;
    const int t = t0 + wave * 16 + l16;
    #pragma unroll
    for (int dt = 0; dt < 4; ++dt) {
        #pragma unroll
        for (int r = 0; r < 4; ++r) {
            int dd = dt * 16 + quad * 4 + r;
            out[((size_t)b * D + hh * DH + dd) * T + t] = O[dt][r] * inv * sv[dd];
        }
    }
}

// -----------------------------------------------------------------------------
extern "C" void kernel_launch(void* const* d_in, const int* in_sizes, int n_in,
                              void* d_out, int out_size, void* d_ws, size_t ws_size,
                              hipStream_t stream) {
    const float* x      = (const float*)d_in[0];
    const float* qkv    = (const float*)d_in[1];
    const float* norm_w = (const float*)d_in[2];
    float* out = (float*)d_out;

    const size_t HB_BYTES = (size_t)2 * B * H * T * DH * 2;   // Q+K slabs
    const size_t VT_BYTES = (size_t)B * H * DH * T * 2;
    const size_t XT_BYTES = (size_t)B * T * D * 2;
    const size_t WT_BYTES = (size_t)3 * H * DH * D * 2;
    ushort* hb  = (ushort*)d_ws;
    ushort* vT  = (ushort*)((char*)d_ws + HB_BYTES);
    ushort* xT  = (ushort*)((char*)d_ws + HB_BYTES + VT_BYTES);
    ushort* WT  = (ushort*)((char*)d_ws + HB_BYTES + VT_BYTES + XT_BYTES);
    float*  ssq = (float*)((char*)d_ws + HB_BYTES + VT_BYTES + XT_BYTES + WT_BYTES);
    const int SSQ_N = 3 * B * H * DH;

    // x transpose also zeroes ssq (block 0) — it strictly precedes qkv_mm.
    transpose_lrelu<<<dim3(T / 64, D / 64, B), 256, 0, stream>>>(
        x, xT, T, D, (size_t)D * T, (size_t)T * D, 1, ssq, SSQ_N);
    transpose_lrelu<<<dim3(DH / 64, D / 64, 3 * H), 256, 0, stream>>>(
        qkv, WT, DH, D, (size_t)D * DH, (size_t)DH * D, 0, nullptr, 0);

    qkv_mm<<<dim3(T / 128, (3 * H * DH) / 128, B), 256, 0, stream>>>(xT, WT, hb, vT, ssq);
    flash_attn<<<dim3((T / 64) * B * H), 256, 0, stream>>>(hb, vT, ssq, norm_w, out);
}